// Round 7
// baseline (105.816 us; speedup 1.0000x reference)
//
#include <hip/hip_runtime.h>
#include <math.h>

typedef float f32x4 __attribute__((ext_vector_type(4)));
typedef short s16x8 __attribute__((ext_vector_type(8)));
typedef unsigned u32x4 __attribute__((ext_vector_type(4)));

#define N_NODES 2048
#define KEDGE 32
#define HDIM 128

__device__ __forceinline__ short f2bf(float f){
  unsigned u = __builtin_bit_cast(unsigned, f);
  u += 0x7fffu + ((u >> 16) & 1u);
  return (short)(u >> 16);
}

__device__ __forceinline__ unsigned cvt_pk_bf16(float a, float b){
  unsigned r;
  asm("v_cvt_pk_bf16_f32 %0, %1, %2" : "=v"(r) : "v"(a), "v"(b));
  return r;
}

// tanh-form GELU via exp2+rcp: max abs error vs exact ~5e-4
__device__ __forceinline__ float fast_gelu(float x){
  float t = x * (-2.3022078f - 0.1029527f * x * x);
  float e = __builtin_amdgcn_exp2f(t);
  return x * __builtin_amdgcn_rcpf(1.0f + e);
}

__device__ __forceinline__ void gld16(const void* g, void* l){
  __builtin_amdgcn_global_load_lds(
      (const __attribute__((address_space(1))) void*)g,
      (__attribute__((address_space(3))) void*)l, 16, 0, 0);
}

__device__ __forceinline__ f32x4 mfma16(s16x8 a, s16x8 b, f32x4 c){
  return __builtin_amdgcn_mfma_f32_16x16x32_bf16(a, b, c, 0, 0, 0);
}

// ---- prep kernel 1: pack W1/W2 to bf16 B-fragment order; init idx flag ----
// elem((ks,ct,lane,j)) = W[ks*32 + (lane>>4)*8 + j][ct*16 + (lane&15)]
__global__ void prep1(const float* __restrict__ W1, const float* __restrict__ W2,
                      short* __restrict__ W1f, short* __restrict__ W2f,
                      unsigned* __restrict__ flag){
  if (blockIdx.x == 320){
    if (threadIdx.x == 0) *flag = 0u;
    return;
  }
  int t = blockIdx.x * 256 + threadIdx.x;
  if (t < 65536){
    int ks = t >> 12, r = t & 4095;
    int ct = r >> 9;  r &= 511;
    int lane = r >> 3, j = r & 7;
    int k = ks*32 + (lane>>4)*8 + j;
    int n = ct*16 + (lane&15);
    W1f[t] = f2bf(W1[k*128 + n]);
  } else if (t < 81920){
    int t2 = t - 65536;
    int ks = t2 >> 12, r = t2 & 4095;
    int ct = r >> 9;  r &= 511;
    int lane = r >> 3, j = r & 7;
    int k = ks*32 + (lane>>4)*8 + j;
    int n = ct*16 + (lane&15);
    W2f[t2] = f2bf(W2[k*128 + n]);
  }
}

// ---- prep kernel 2: Z/U tables (blocks 0..127) + E_idx dtype detect (128..639)
//   Z[m]  = hS(m)@W1c + hV(m)@W1d   (f32, 128)
//   U'[m] = hV(m)@W1a + b1          (f32, 128)
__global__ __launch_bounds__(256)
void prep2(const float* __restrict__ hS, const float* __restrict__ hV,
           const float* __restrict__ b1, const short* __restrict__ W1f,
           float* __restrict__ Z, float* __restrict__ U,
           const unsigned* __restrict__ Ei_u, unsigned* __restrict__ flag){
  if (blockIdx.x >= 128){
    int t = ((int)blockIdx.x - 128)*256 + threadIdx.x;   // t < 131072
    unsigned v = Ei_u[2*t + 1];
    unsigned long long m = __ballot(v != 0u);
    if ((threadIdx.x & 63) == 0 && m) atomicOr(flag, 1u);
    return;
  }
  const int tid = threadIdx.x;
  const int w = tid >> 6, lane = tid & 63, l15 = lane & 15, lg = lane >> 4;
  const int nb = ((int)blockIdx.x*4 + w)*16;

  f32x4 accz[8], accu[8];
  #pragma unroll
  for (int ct = 0; ct < 8; ++ct){ accz[ct] = (f32x4){0,0,0,0}; accu[ct] = (f32x4){0,0,0,0}; }

  #pragma unroll
  for (int ks = 0; ks < 4; ++ks){
    const float* p = hS + (long)(nb + l15)*128 + ks*32 + lg*8;
    float4 x = *(const float4*)p, y = *(const float4*)(p + 4);
    u32x4 pk;
    pk[0] = cvt_pk_bf16(x.x, x.y); pk[1] = cvt_pk_bf16(x.z, x.w);
    pk[2] = cvt_pk_bf16(y.x, y.y); pk[3] = cvt_pk_bf16(y.z, y.w);
    s16x8 a = __builtin_bit_cast(s16x8, pk);
    #pragma unroll
    for (int ct = 0; ct < 8; ++ct){
      s16x8 bf = *(const s16x8*)(W1f + (8+ks)*4096 + ct*512 + lane*8);
      accz[ct] = mfma16(a, bf, accz[ct]);
    }
  }
  #pragma unroll
  for (int ks = 0; ks < 4; ++ks){
    const float* p = hV + (long)(nb + l15)*128 + ks*32 + lg*8;
    float4 x = *(const float4*)p, y = *(const float4*)(p + 4);
    u32x4 pk;
    pk[0] = cvt_pk_bf16(x.x, x.y); pk[1] = cvt_pk_bf16(x.z, x.w);
    pk[2] = cvt_pk_bf16(y.x, y.y); pk[3] = cvt_pk_bf16(y.z, y.w);
    s16x8 a = __builtin_bit_cast(s16x8, pk);
    #pragma unroll
    for (int ct = 0; ct < 8; ++ct){
      s16x8 bfd = *(const s16x8*)(W1f + (12+ks)*4096 + ct*512 + lane*8);
      accz[ct] = mfma16(a, bfd, accz[ct]);
      s16x8 bfa = *(const s16x8*)(W1f + (0+ks)*4096 + ct*512 + lane*8);
      accu[ct] = mfma16(a, bfa, accu[ct]);
    }
  }

  float b1v[8];
  #pragma unroll
  for (int ct = 0; ct < 8; ++ct) b1v[ct] = b1[ct*16 + l15];

  #pragma unroll
  for (int ct = 0; ct < 8; ++ct)
    #pragma unroll
    for (int i = 0; i < 4; ++i){
      const long row = nb + lg*4 + i;
      Z[row*128 + ct*16 + l15] = accz[ct][i];
      U[row*128 + ct*16 + l15] = accu[ct][i] + b1v[ct];
    }
}

// ---- fused kernel: wave = 16 edges (half a node). ALL hot data staged to
// LDS via global_load_lds (16 gld16 = 16 KB in flight per wave, zero VGPR
// cost, compiler cannot sink). One vmcnt(0) drain, then LDS-local compute.
// Granule XOR g^(row&6) folded into the per-lane global SOURCE address
// (m173 pattern) de-conflicts the strided ds_read_b128s.
__global__ __launch_bounds__(256, 2)
void fusedF(const float* __restrict__ hE, const int* __restrict__ Eidx,
            const float* __restrict__ mask, const float* __restrict__ hV,
            const float* __restrict__ W2b, const float* __restrict__ lng,
            const float* __restrict__ lnb, const short* __restrict__ W1f,
            const short* __restrict__ W2f, const float* __restrict__ Z,
            const float* __restrict__ U, const unsigned* __restrict__ idx_flag,
            float* __restrict__ out)
{
  __shared__ __align__(16) char smem[67584];  // 4 x 16KB staging + 2KB v-exchange

  const int tid  = threadIdx.x;
  const int w    = tid >> 6;          // 4 waves; waves (0,1) node A, (2,3) node B
  const int lane = tid & 63;
  const int l15  = lane & 15;
  const int lg   = lane >> 4;
  const int h    = w & 1;             // which 16-edge half

  const int bid  = (int)blockIdx.x;
  const int bswz = (bid & 7)*512 + (bid >> 3);   // XCD swizzle (4096 % 8 == 0)
  const int ng   = bswz*2 + (w >> 1);
  const int b    = ng >> 11;
  const long nodeoff = (long)ng * HDIM;
  const int  ebase   = ng * KEDGE;

  char* wbase = smem + w*16384;
  const int rr = lane >> 5;           // sub-row within 1KB chunk
  const int g  = lane & 31;           // 16B granule within 512B row

  // ---- stage hE: 16 edge-rows x 512B, source granule-swizzled ----
  #pragma unroll
  for (int q = 0; q < 8; ++q){
    const int r = 2*q + rr;
    const float* src = hE + (((long)(ebase + h*16 + r)) << 7) + ((g ^ (r & 6)) << 2);
    gld16(src, wbase + q*1024);
  }

  // flag -> eidx -> Z staging chain (latency hidden under hE drain)
  const int is64 = (*idx_flag == 0u);
  const int er   = ebase + h*16 + l15;
  const int eidx = is64 ? Eidx[2*er] : Eidx[er];
  const float mval = mask[er];

  // ---- stage Z[idx] gather rows: per-lane global source, linear LDS dest ----
  #pragma unroll
  for (int q = 0; q < 8; ++q){
    const int r = 2*q + rr;
    const int e_r = __shfl(eidx, 2*q + rr, 64);   // eidx of edge-row r
    const float* src = Z + (((long)(b*N_NODES + e_r)) << 7) + ((g ^ (r & 6)) << 2);
    gld16(src, wbase + 8192 + q*1024);
  }

  // U row + hV row (consumed post-GEMM; latency hidden under drain)
  float uv[8], hvv[8];
  #pragma unroll
  for (int ct = 0; ct < 8; ++ct){
    uv[ct]  = U[nodeoff + ct*16 + l15];
    hvv[ct] = hV[nodeoff + ct*16 + l15];
  }

  // identity B-fragments for Z injection (exact in bf16)
  s16x8 ifr[2];
  #pragma unroll
  for (int c2 = 0; c2 < 2; ++c2){
    const int active = ((lg >> 1) == c2);
    const int j = l15 - 8*(lg & 1);
    s16x8 f;
    #pragma unroll
    for (int e = 0; e < 8; ++e)
      f[e] = (active && j == e) ? (short)0x3F80 : (short)0;
    ifr[c2] = f;
  }

  // single structural drain: all 16KB of staged data now in LDS
  asm volatile("s_waitcnt vmcnt(0)" ::: "memory");
  __builtin_amdgcn_sched_barrier(0);

  // ---- GEMM1: pre-act = mask*(hE@W1b) + mask*Z[idx]  (U added at gelu) ----
  f32x4 acc1[8];
  #pragma unroll
  for (int ct = 0; ct < 8; ++ct) acc1[ct] = (f32x4){0,0,0,0};

  const short* Wb = W1f + 16384;      // packed W1b region (ks 4..7)

  #pragma unroll
  for (int ks = 0; ks < 4; ++ks){
    const int gsw = ((ks*8 + lg*2) ^ (l15 & 6)) << 4;
    // hE A-fragment from LDS
    const char* pe = wbase + l15*512 + gsw;
    float4 ex = *(const float4*)pe;
    float4 ey = *(const float4*)(pe + 16);
    u32x4 pk;
    pk[0] = cvt_pk_bf16(ex.x*mval, ex.y*mval); pk[1] = cvt_pk_bf16(ex.z*mval, ex.w*mval);
    pk[2] = cvt_pk_bf16(ey.x*mval, ey.y*mval); pk[3] = cvt_pk_bf16(ey.z*mval, ey.w*mval);
    s16x8 a = __builtin_bit_cast(s16x8, pk);

    const short* bb = Wb + ks*4096 + lane*8;
    #pragma unroll
    for (int ct = 0; ct < 8; ++ct){
      s16x8 bf = *(const s16x8*)(bb + ct*512);
      acc1[ct] = mfma16(a, bf, acc1[ct]);
    }

    // Z A-fragment + identity injection into cols ct = 2ks, 2ks+1
    const char* pz = wbase + 8192 + l15*512 + gsw;
    float4 zx = *(const float4*)pz;
    float4 zy = *(const float4*)(pz + 16);
    u32x4 zk;
    zk[0] = cvt_pk_bf16(zx.x*mval, zx.y*mval); zk[1] = cvt_pk_bf16(zx.z*mval, zx.w*mval);
    zk[2] = cvt_pk_bf16(zy.x*mval, zy.y*mval); zk[3] = cvt_pk_bf16(zy.z*mval, zy.w*mval);
    s16x8 az = __builtin_bit_cast(s16x8, zk);
    #pragma unroll
    for (int c2 = 0; c2 < 2; ++c2)
      acc1[ks*2 + c2] = mfma16(az, ifr[c2], acc1[ks*2 + c2]);
  }

  // ---- U' + GELU, reduce over this wave's 16 edges in registers ----
  float v8[8];
  #pragma unroll
  for (int ct = 0; ct < 8; ++ct){
    float s = 0.f;
    #pragma unroll
    for (int i = 0; i < 4; ++i)
      s += fast_gelu(acc1[ct][i] + uv[ct]);
    s += __shfl_xor(s, 16, 64);
    s += __shfl_xor(s, 32, 64);              // col = ct*16 + l15, replicated
    v8[ct] = s;
  }

  // ---- exchange partial v with partner wave (other 16 edges) ----
  float* vex = (float*)(smem + 65536) + w*128;
  if (lg == 0){
    #pragma unroll
    for (int ct = 0; ct < 8; ++ct) vex[ct*16 + l15] = v8[ct];
  }
  __syncthreads();
  const float* vexP = (float*)(smem + 65536) + (w^1)*128;

  // ---- GEMM2: v (replicated rows) @ W2 ----
  s16x8 av[4];
  #pragma unroll
  for (int ks2 = 0; ks2 < 4; ++ks2){
    const int off = ks2*32 + lg*8;           // uniform across l15 (broadcast)
    float4 a0 = *(const float4*)(vex + off);
    float4 a1 = *(const float4*)(vex + off + 4);
    float4 b0 = *(const float4*)(vexP + off);
    float4 b1 = *(const float4*)(vexP + off + 4);
    u32x4 pk;
    pk[0] = cvt_pk_bf16(a0.x+b0.x, a0.y+b0.y);
    pk[1] = cvt_pk_bf16(a0.z+b0.z, a0.w+b0.w);
    pk[2] = cvt_pk_bf16(a1.x+b1.x, a1.y+b1.y);
    pk[3] = cvt_pk_bf16(a1.z+b1.z, a1.w+b1.w);
    av[ks2] = __builtin_bit_cast(s16x8, pk);
  }

  f32x4 acc2[8];
  #pragma unroll
  for (int ct = 0; ct < 8; ++ct) acc2[ct] = (f32x4){0,0,0,0};

  #pragma unroll
  for (int ks2 = 0; ks2 < 4; ++ks2){
    const short* wb2 = W2f + ks2*4096 + lane*8;
    #pragma unroll
    for (int ct = 0; ct < 8; ++ct){
      s16x8 bf = *(const s16x8*)(wb2 + ct*512);
      acc2[ct] = mfma16(av[ks2], bf, acc2[ct]);
    }
  }

  // ---- epilogue: + 32*b2, /30, + h_V, LayerNorm; h==0 wave stores ----
  float res[8];
  float vs = 0.f, vq = 0.f;
  #pragma unroll
  for (int ct = 0; ct < 8; ++ct){
    const int c = ct*16 + l15;
    float dh  = (acc2[ct][0] + 32.0f * W2b[c]) * (1.0f/30.0f);
    float val = hvv[ct] + dh;
    res[ct] = val;
    vs += val; vq += val*val;
  }
  vs += __shfl_xor(vs, 1, 64);  vs += __shfl_xor(vs, 2, 64);
  vs += __shfl_xor(vs, 4, 64);  vs += __shfl_xor(vs, 8, 64);
  vq += __shfl_xor(vq, 1, 64);  vq += __shfl_xor(vq, 2, 64);
  vq += __shfl_xor(vq, 4, 64);  vq += __shfl_xor(vq, 8, 64);
  const float mu  = vs * (1.0f/128.0f);
  const float var = vq * (1.0f/128.0f) - mu*mu;
  const float rs  = rsqrtf(var + 1e-5f);

  if (h == 0){
    #pragma unroll
    for (int q = 0; q < 2; ++q){
      const int ct = lg*2 + q;
      const int c  = ct*16 + l15;
      out[nodeoff + c] = (res[ct] - mu) * rs * lng[c] + lnb[c];
    }
  }
}

extern "C" void kernel_launch(void* const* d_in, const int* in_sizes, int n_in,
                              void* d_out, int out_size, void* d_ws, size_t ws_size,
                              hipStream_t stream) {
  const float* hS  = (const float*)d_in[0];
  const float* hV  = (const float*)d_in[1];
  const float* hE  = (const float*)d_in[2];
  const int*   Ei  = (const int*)d_in[3];
  const float* mk  = (const float*)d_in[4];
  const float* W1w = (const float*)d_in[5];
  const float* W1b = (const float*)d_in[6];
  const float* W2w = (const float*)d_in[7];
  const float* W2b = (const float*)d_in[8];
  const float* lng = (const float*)d_in[9];
  const float* lnb = (const float*)d_in[10];

  short* W1f = (short*)d_ws;                         // 131072 B
  short* W2f = W1f + 65536;                          // 32768 B
  unsigned* flag = (unsigned*)((char*)d_ws + 163840);
  float* Z = (float*)((char*)d_ws + 164096);         // 4 MB
  float* U = Z + 1048576;                            // 4 MB

  prep1<<<321, 256, 0, stream>>>(W1w, W2w, W1f, W2f, flag);
  prep2<<<640, 256, 0, stream>>>(hS, hV, W1b, W1f, Z, U, (const unsigned*)Ei, flag);
  fusedF<<<4096, 256, 0, stream>>>(hE, Ei, mk, hV, W2b, lng, lnb,
                                   W1f, W2f, Z, U, flag, (float*)d_out);
}